// Round 5
// baseline (551.618 us; speedup 1.0000x reference)
//
#include <hip/hip_runtime.h>

#define BATCH 524288
#define NF 128
#define WPITCH 136            // bf16 elems per LDS row: 128 + 8 pad -> 272 B pitch
#define NTILES (BATCH / 64)   // 8192 row-tiles of 64 rows
#define GRID 1024             // 8 tiles per block; 4 blocks/CU resident, one generation

typedef __attribute__((ext_vector_type(8))) short bf16x8;
typedef __attribute__((ext_vector_type(4))) float f32x4;

__device__ __forceinline__ unsigned short f2bf(float f) {
    union { float f; unsigned u; } c; c.f = f;
    unsigned r = c.u + 0x7fffu + ((c.u >> 16) & 1u);   // round-to-nearest-even
    return (unsigned short)(r >> 16);
}
__device__ __forceinline__ unsigned pk2(float lo, float hi) {
    return (unsigned)f2bf(lo) | ((unsigned)f2bf(hi) << 16);
}

// Block = 4 waves; each wave owns 16 batch rows per tile; block tile = 64 rows.
// vs round-4 verified kernel: identical math/layout, but grid-strided so W is
// staged ONCE per block (1024 stagings instead of 8192) and 7/8 of tiles run
// with no barrier in the loop body.
// MFMA: A = W (LDS), B = x. C/D mapping (col=lane&15, row=quad*4+reg) gives
// C[o_local][batch]: each lane holds 4 contiguous outputs along o -> f32x4 stores.
__global__ __launch_bounds__(256, 4) void linear_kernel(
    const float* __restrict__ x, const float* __restrict__ w,
    const float* __restrict__ bias, float* __restrict__ out)
{
    __shared__ unsigned short wlds[NF * WPITCH];

    const int tid = threadIdx.x;

    // ---- Stage W (128x128 fp32 row-major [o][i]) -> LDS bf16, once per block ----
    for (int i = tid; i < NF * NF / 4; i += 256) {
        const float4 v = ((const float4*)w)[i];
        const int r = i >> 5;          // 32 float4 per row
        const int c = (i & 31) << 2;
        uint2 pv;
        pv.x = pk2(v.x, v.y);
        pv.y = pk2(v.z, v.w);
        *(uint2*)&wlds[r * WPITCH + c] = pv;   // 8B aligned: 272*r + 2c
    }

    const int lane = tid & 63;
    const int wave = tid >> 6;
    const int bl   = lane & 15;   // fragment row index (both operands); C col = batch lane
    const int quad = lane >> 4;

    // Bias folded into accumulator init: lane's outputs are o = t*16 + quad*4 + r.
    f32x4 bfrag[8];
#pragma unroll
    for (int t = 0; t < 8; t++)
        bfrag[t] = *(const f32x4*)(bias + t * 16 + quad * 4);

    __syncthreads();   // W staged; LDS read-only hereafter (only barrier in kernel)

    for (int tile = blockIdx.x; tile < NTILES; tile += GRID) {
        const size_t row = (size_t)tile * 64 + wave * 16 + bl;
        const float* xrow = x + row * NF;

        f32x4 acc[8];
#pragma unroll
        for (int t = 0; t < 8; t++) acc[t] = bfrag[t];

#pragma unroll
        for (int kk = 0; kk < 4; kk++) {
            const int kbase = kk * 32 + quad * 8;

            // x fragment (B operand): 8 contiguous fp32 from this lane's row
            const float4 a0 = *(const float4*)(xrow + kbase);
            const float4 a1 = *(const float4*)(xrow + kbase + 4);
            union { bf16x8 v; unsigned u[4]; } xf;
            xf.u[0] = pk2(a0.x, a0.y);
            xf.u[1] = pk2(a0.z, a0.w);
            xf.u[2] = pk2(a1.x, a1.y);
            xf.u[3] = pk2(a1.z, a1.w);

#pragma unroll
            for (int t = 0; t < 8; t++) {
                // W fragment (A operand): W[o = t*16 + bl][kbase..kbase+7]
                const bf16x8 wf = *(const bf16x8*)&wlds[(t * 16 + bl) * WPITCH + kbase];
                acc[t] = __builtin_amdgcn_mfma_f32_16x16x32_bf16(wf, xf.v, acc[t], 0, 0, 0);
            }
        }

        // ---- Epilogue: lane owns out[row][t*16 + quad*4 .. +3] -> float4 stores ----
        float* orow = out + row * NF + quad * 4;
#pragma unroll
        for (int t = 0; t < 8; t++)
            *(f32x4*)(orow + t * 16) = acc[t];
    }
}

extern "C" void kernel_launch(void* const* d_in, const int* in_sizes, int n_in,
                              void* d_out, int out_size, void* d_ws, size_t ws_size,
                              hipStream_t stream) {
    const float* x    = (const float*)d_in[0];   // enc_x  (524288, 128)
    const float* w    = (const float*)d_in[1];   // weight (128, 128)
    const float* bias = (const float*)d_in[2];   // bias   (128,)
    float* out = (float*)d_out;                  // (524288, 128)

    linear_kernel<<<GRID, 256, 0, stream>>>(x, w, bias, out);
}

// Round 6
// 442.337 us; speedup vs baseline: 1.2471x; 1.2471x over previous
//
#include <hip/hip_runtime.h>

#define BATCH 524288
#define NF 128
#define WPITCH 136   // bf16 elems per LDS row for W: 128 + 8 pad -> 272 B pitch
#define CPITCH 132   // f32 elems per LDS row for C staging: 128 + 4 pad -> 528 B pitch

typedef __attribute__((ext_vector_type(8))) short bf16x8;
typedef __attribute__((ext_vector_type(4))) float f32x4;

__device__ __forceinline__ unsigned short f2bf(float f) {
    union { float f; unsigned u; } c; c.f = f;
    unsigned r = c.u + 0x7fffu + ((c.u >> 16) & 1u);   // round-to-nearest-even
    return (unsigned short)(r >> 16);
}
__device__ __forceinline__ unsigned pk2(float lo, float hi) {
    return (unsigned)f2bf(lo) | ((unsigned)f2bf(hi) << 16);
}

// Block = 4 waves = 64 batch rows, grid = BATCH/64 = 8192 (round-4 proven shape;
// persistent-block GRID=1024 regressed 2x: latency-bound at 3.3 TB/s).
// MFMA: A = W (LDS), B = x. C/D mapping (col=lane&15, row=quad*4+reg) gives
// C[o_local][batch]: lane (bl,quad) holds out[row=bl][o=t*16+quad*4..+3].
// NEW vs round-4: epilogue goes through LDS so each wave store instruction
// writes 1024 CONTIGUOUS bytes (2 full output rows = 8 whole 128B lines).
// Round-5 counters showed direct 64B-per-row stores cost ~208 MiB of
// read-for-ownership FETCH + ~76 MiB extra WRITE (partial-line evictions).
__global__ __launch_bounds__(256, 4) void linear_kernel(
    const float* __restrict__ x, const float* __restrict__ w,
    const float* __restrict__ bias, float* __restrict__ out)
{
    // 34816 B. Reused for C staging after MFMAs (needs 4*16*CPITCH*4 = 33792 B).
    __shared__ unsigned short wlds[NF * WPITCH];

    const int tid = threadIdx.x;

    // ---- Stage W (128x128 fp32, row-major [o][i]) -> LDS bf16 ----
    for (int i = tid; i < NF * NF / 4; i += 256) {
        const float4 v = ((const float4*)w)[i];
        const int r = i >> 5;          // 32 float4 per row
        const int c = (i & 31) << 2;
        uint2 pv;
        pv.x = pk2(v.x, v.y);
        pv.y = pk2(v.z, v.w);
        *(uint2*)&wlds[r * WPITCH + c] = pv;   // 8B aligned
    }

    const int lane = tid & 63;
    const int wave = tid >> 6;
    const int bl   = lane & 15;   // fragment row index (both operands); C col = batch lane
    const int quad = lane >> 4;

    // Bias folded into accumulator init: lane's outputs are o = t*16 + quad*4 + r.
    f32x4 bfrag[8];
#pragma unroll
    for (int t = 0; t < 8; t++)
        bfrag[t] = *(const f32x4*)(bias + t * 16 + quad * 4);

    __syncthreads();   // W staged

    const size_t rowbase = (size_t)blockIdx.x * 64 + wave * 16;
    const float* xrow = x + (rowbase + bl) * NF;

    f32x4 acc[8];
#pragma unroll
    for (int t = 0; t < 8; t++) acc[t] = bfrag[t];

#pragma unroll
    for (int kk = 0; kk < 4; kk++) {
        const int kbase = kk * 32 + quad * 8;

        // x fragment (B operand): 8 contiguous fp32 from this lane's row
        const float4 a0 = *(const float4*)(xrow + kbase);
        const float4 a1 = *(const float4*)(xrow + kbase + 4);
        union { bf16x8 v; unsigned u[4]; } xf;
        xf.u[0] = pk2(a0.x, a0.y);
        xf.u[1] = pk2(a0.z, a0.w);
        xf.u[2] = pk2(a1.x, a1.y);
        xf.u[3] = pk2(a1.z, a1.w);

#pragma unroll
        for (int t = 0; t < 8; t++) {
            // W fragment (A operand): W[o = t*16 + bl][kbase..kbase+7]
            const bf16x8 wf = *(const bf16x8*)&wlds[(t * 16 + bl) * WPITCH + kbase];
            acc[t] = __builtin_amdgcn_mfma_f32_16x16x32_bf16(wf, xf.v, acc[t], 0, 0, 0);
        }
    }

    __syncthreads();   // all waves done reading W -> safe to overwrite with C

    // ---- Epilogue via LDS: fragment layout -> row-linear full-line stores ----
    // Each wave owns a disjoint 16 x CPITCH f32 region; write->read is ordered
    // by in-wave lgkmcnt (no second barrier needed).
    float* cw = (float*)wlds + wave * (16 * CPITCH);

#pragma unroll
    for (int t = 0; t < 8; t++)
        *(f32x4*)(cw + bl * CPITCH + t * 16 + quad * 4) = acc[t];

    const int half = lane >> 5;          // which row of the pair
    const int c4   = (lane & 31) << 2;   // float column, 16B per lane
#pragma unroll
    for (int i = 0; i < 8; i++) {
        const int r = 2 * i + half;      // wave-local row 0..15
        const f32x4 v = *(const f32x4*)(cw + r * CPITCH + c4);
        // wave writes rows (rowbase+2i, rowbase+2i+1): 1024B contiguous
        *(f32x4*)(out + (rowbase + r) * NF + c4) = v;
    }
}

extern "C" void kernel_launch(void* const* d_in, const int* in_sizes, int n_in,
                              void* d_out, int out_size, void* d_ws, size_t ws_size,
                              hipStream_t stream) {
    const float* x    = (const float*)d_in[0];   // enc_x  (524288, 128)
    const float* w    = (const float*)d_in[1];   // weight (128, 128)
    const float* bias = (const float*)d_in[2];   // bias   (128,)
    float* out = (float*)d_out;                  // (524288, 128)

    linear_kernel<<<BATCH / 64, 256, 0, stream>>>(x, w, bias, out);
}